// Round 5
// baseline (264.891 us; speedup 1.0000x reference)
//
#include <hip/hip_runtime.h>
#include <hip/hip_bf16.h>

#define NN 2560        // nodes
#define NE 163840      // edges
#define NH 4           // heads
#define NC 128         // channels per head
#define NF 512         // NH*NC
#define OUTE 40
#define CSTR 256       // fixed CSR stride per node; deg>CSTR -> overflow list
#define NCOPY 16       // striped BN-stat copies: 2560/16 = 160 RMWs/address

typedef short bf16x8 __attribute__((ext_vector_type(8)));
typedef float f32x4 __attribute__((ext_vector_type(4)));

__device__ inline ushort f2bf(float f) {
    uint u = __float_as_uint(f);
    uint r = u + 0x7FFF + ((u >> 16) & 1);   // round-to-nearest-even
    return (ushort)(r >> 16);
}
__device__ inline float bflo(uint v) { return __uint_as_float(v << 16); }
__device__ inline float bfhi(uint v) { return __uint_as_float(v & 0xFFFF0000u); }
__device__ inline float bf2f(ushort u) { return __uint_as_float(((uint)u) << 16); }
__device__ inline float rdlanef(float v, int l) {
    return __int_as_float(__builtin_amdgcn_readlane(__float_as_int(v), l));
}
__device__ inline int rdlanei(int v, int l) {
    return __builtin_amdgcn_readlane(v, l);
}
// 4-way select by per-lane-constant head index (3 cndmask, masks hoisted)
__device__ inline float sel4(float r0, float r1, float r2, float r3, int hd) {
    return (hd & 2) ? ((hd & 1) ? r3 : r2) : ((hd & 1) ? r1 : r0);
}

// ---------------- kernel 1: CSR fill (single-pass) + dote/WfcT/W2T + GEMM1+att
__global__ __launch_bounds__(256) void k_csr_gemm1(const int* __restrict__ ei,
        const float* __restrict__ pos, int* __restrict__ deg,
        int2* __restrict__ csrp, int* __restrict__ ovf_cnt, int4* __restrict__ ovf,
        const float* __restrict__ We1, const float* __restrict__ ae1,
        const float* __restrict__ We2, const float* __restrict__ ae2,
        float* __restrict__ dote,
        const float* __restrict__ Wfc, ushort* __restrict__ WfcT,
        const float* __restrict__ W2, ushort* __restrict__ W2T,
        const float* __restrict__ x, const float* __restrict__ W1,
        const float* __restrict__ atts, const float* __restrict__ attd,
        ushort* __restrict__ hb, float* __restrict__ as_, float* __restrict__ ad_) {
    __shared__ ushort tile[64][72];
    __shared__ float s_x[4][32];
    __shared__ float4 s_red[4][4];     // [wave][node]
    int b = blockIdx.x;
    if (b < 640) {
        int e = b * 256 + threadIdx.x;
        int s = ei[e], d = ei[NE + e];
        float dx = pos[2 * s] - pos[2 * d];
        float dy = pos[2 * s + 1] - pos[2 * d + 1];
        float w = 1.0f / (sqrtf(dx * dx + dy * dy) + 1e-6f);
        int r = atomicAdd(&deg[d], 1);     // slot + degree in one pass
        if (r < CSTR) {
            csrp[(d << 8) + r] = make_int2(s, __float_as_int(w));
        } else {                            // pathological deg > CSTR: exact fallback
            int i = atomicAdd(ovf_cnt, 1);
            ovf[i] = make_int4(d, s, __float_as_int(w), 0);
        }
        return;
    }
    if (b < 642) {
        int t = threadIdx.x;
        const float* W = (b == 641) ? We2 : We1;
        const float* A = (b == 641) ? ae2 : ae1;
        int w = t >> 6, l = t & 63;
        float p = W[w * 128 + l] * A[w * 128 + l] + W[w * 128 + 64 + l] * A[w * 128 + 64 + l];
#pragma unroll
        for (int o = 32; o > 0; o >>= 1) p += __shfl_down(p, o);
        if (l == 0) dote[(b - 640) * 4 + w] = p;
        return;
    }
    if (b < 738) {
        int idx = (b - 642) * 256 + threadIdx.x;    // j*512 + k
        int j = idx >> 9, k = idx & 511;
        WfcT[idx] = (j < OUTE) ? f2bf(Wfc[k * OUTE + j]) : (ushort)0;
        return;
    }
    if (b < 802) {
        int id = b - 738;
        int n0 = (id & 7) * 64, k0 = (id >> 3) * 64;
        int t = threadIdx.x;
        int r = t >> 2, cseg = (t & 3) * 16;
#pragma unroll
        for (int c = 0; c < 16; c += 4) {
            float4 v = *(const float4*)&W2[(k0 + r) * 512 + n0 + cseg + c];
            tile[cseg + c + 0][r] = f2bf(v.x);
            tile[cseg + c + 1][r] = f2bf(v.y);
            tile[cseg + c + 2][r] = f2bf(v.z);
            tile[cseg + c + 3][r] = f2bf(v.w);
        }
        __syncthreads();
        *(uint4*)&W2T[(n0 + r) * 512 + k0 + cseg]     = *(uint4*)&tile[r][cseg];
        *(uint4*)&W2T[(n0 + r) * 512 + k0 + cseg + 8] = *(uint4*)&tile[r][cseg + 8];
        return;
    }
    int n0 = (b - 802) * 4, t = threadIdx.x;
    if (t < 128) s_x[t >> 5][t & 31] = x[n0 * 32 + t];
    __syncthreads();
    float a0[4] = {0.f, 0.f, 0.f, 0.f}, a1[4] = {0.f, 0.f, 0.f, 0.f};
#pragma unroll
    for (int k = 0; k < 32; k++) {
        float w0 = W1[k * 512 + t];
        float w1 = W1[k * 512 + t + 256];
#pragma unroll
        for (int nn = 0; nn < 4; nn++) {
            a0[nn] += s_x[nn][k] * w0;
            a1[nn] += s_x[nn][k] * w1;
        }
    }
    float sa0 = atts[t], sa1 = atts[t + 256];
    float da0 = attd[t], da1 = attd[t + 256];
    int w = t >> 6, lane = t & 63;
#pragma unroll
    for (int nn = 0; nn < 4; nn++) {
        hb[(n0 + nn) * 512 + t] = f2bf(a0[nn]);
        hb[(n0 + nn) * 512 + t + 256] = f2bf(a1[nn]);
        float ps0 = a0[nn] * sa0, pd0 = a0[nn] * da0;
        float ps1 = a1[nn] * sa1, pd1 = a1[nn] * da1;
#pragma unroll
        for (int o = 32; o > 0; o >>= 1) {
            ps0 += __shfl_xor(ps0, o); pd0 += __shfl_xor(pd0, o);
            ps1 += __shfl_xor(ps1, o); pd1 += __shfl_xor(pd1, o);
        }
        if (lane == 0) s_red[w][nn] = make_float4(ps0, pd0, ps1, pd1);
    }
    __syncthreads();
    if (t < 4) {
        int nn = t, n = n0 + nn;
        float4 r0 = s_red[0][nn], r1 = s_red[1][nn], r2 = s_red[2][nn], r3 = s_red[3][nn];
        as_[n * 4 + 0] = r0.x + r1.x; as_[n * 4 + 1] = r2.x + r3.x;
        as_[n * 4 + 2] = r0.z + r1.z; as_[n * 4 + 3] = r2.z + r3.z;
        ad_[n * 4 + 0] = r0.y + r1.y; ad_[n * 4 + 1] = r2.y + r3.y;
        ad_[n * 4 + 2] = r0.w + r1.w; ad_[n * 4 + 3] = r2.w + r3.w;
    }
}

// ---------------- kernel 2: softmax+agg, block = node (2 waves x 64 edges) -
// R25: keeps R24's halved per-edge instruction count (uint4, all 4 heads per
// wave) but restores 5120 waves for gather-latency hiding (R4 null result:
// 2.5 waves/SIMD couldn't hide L2/L3 gather latency). Fused striped BN-stats
// (NCOPY=16 -> 160 RMWs/address, same contention as old k_bnstats).
__global__ __launch_bounds__(128) void k_edge_agg(const int* __restrict__ deg_,
        const int2* __restrict__ csrp, const int* __restrict__ ovf_cnt,
        const int4* __restrict__ ovf, const float* __restrict__ as_,
        const float* __restrict__ ad_, const float* __restrict__ dote,
        const ushort* __restrict__ hb, const float* __restrict__ bias,
        ushort* __restrict__ outb, float* __restrict__ stats) {
    __shared__ float s_comb[64][8];      // wave-1 partial acc (2 KB)
    __shared__ float s_red[2][8];        // cross-wave mx / sum exchange
    __shared__ float s_sum[512];         // stats partials (rounded values)
    __shared__ float s_sq[512];
    int w = threadIdx.x >> 6, lane = threadIdx.x & 63;
    int n = blockIdx.x;
    int beg = n << 8;
    int degn = deg_[n];
    int dmain = min(degn, CSTR);
    float4 adv = *(const float4*)&ad_[n * 4];
    float4 dv  = *(const float4*)dote;
    // ---- phase A: this wave's edge = w*64+lane; cold strided by 128 ----
    float La0 = -1e30f, La1 = -1e30f, La2 = -1e30f, La3 = -1e30f;
    int off0 = 0;
    int e0 = w * 64 + lane;
    if (e0 < dmain) {
        int2 p = csrp[beg + e0];
        off0 = p.x * NF;
        float4 a = *(const float4*)&as_[p.x * 4];
        float ww = __int_as_float(p.y);
        float v0 = a.x + adv.x + ww * dv.x; La0 = v0 > 0.f ? v0 : 0.2f * v0;
        float v1 = a.y + adv.y + ww * dv.y; La1 = v1 > 0.f ? v1 : 0.2f * v1;
        float v2 = a.z + adv.z + ww * dv.z; La2 = v2 > 0.f ? v2 : 0.2f * v2;
        float v3 = a.w + adv.w + ww * dv.w; La3 = v3 > 0.f ? v3 : 0.2f * v3;
    }
    float mx0 = La0, mx1 = La1, mx2 = La2, mx3 = La3;
    for (int e = 128 + w * 64 + lane; e < dmain; e += 128) {   // cold: deg > 128
        int2 p = csrp[beg + e];
        float4 a = *(const float4*)&as_[p.x * 4];
        float ww = __int_as_float(p.y);
        float v0 = a.x + adv.x + ww * dv.x; v0 = v0 > 0.f ? v0 : 0.2f * v0;
        float v1 = a.y + adv.y + ww * dv.y; v1 = v1 > 0.f ? v1 : 0.2f * v1;
        float v2 = a.z + adv.z + ww * dv.z; v2 = v2 > 0.f ? v2 : 0.2f * v2;
        float v3 = a.w + adv.w + ww * dv.w; v3 = v3 > 0.f ? v3 : 0.2f * v3;
        mx0 = fmaxf(mx0, v0); mx1 = fmaxf(mx1, v1);
        mx2 = fmaxf(mx2, v2); mx3 = fmaxf(mx3, v3);
    }
    if (degn > CSTR) {                                         // pathological
        int oc = *ovf_cnt;
        for (int i = threadIdx.x; i < oc; i += 128) {
            int4 o = ovf[i];
            if (o.x == n) {
                float4 a = *(const float4*)&as_[o.y * 4];
                float ww = __int_as_float(o.z);
                float v0 = a.x + adv.x + ww * dv.x; v0 = v0 > 0.f ? v0 : 0.2f * v0;
                float v1 = a.y + adv.y + ww * dv.y; v1 = v1 > 0.f ? v1 : 0.2f * v1;
                float v2 = a.z + adv.z + ww * dv.z; v2 = v2 > 0.f ? v2 : 0.2f * v2;
                float v3 = a.w + adv.w + ww * dv.w; v3 = v3 > 0.f ? v3 : 0.2f * v3;
                mx0 = fmaxf(mx0, v0); mx1 = fmaxf(mx1, v1);
                mx2 = fmaxf(mx2, v2); mx3 = fmaxf(mx3, v3);
            }
        }
    }
#pragma unroll
    for (int o = 32; o > 0; o >>= 1) {
        mx0 = fmaxf(mx0, __shfl_xor(mx0, o));
        mx1 = fmaxf(mx1, __shfl_xor(mx1, o));
        mx2 = fmaxf(mx2, __shfl_xor(mx2, o));
        mx3 = fmaxf(mx3, __shfl_xor(mx3, o));
    }
    if (lane == 0) {
        s_red[w][0] = mx0; s_red[w][1] = mx1; s_red[w][2] = mx2; s_red[w][3] = mx3;
    }
    __syncthreads();
    mx0 = fmaxf(s_red[0][0], s_red[1][0]); mx1 = fmaxf(s_red[0][1], s_red[1][1]);
    mx2 = fmaxf(s_red[0][2], s_red[1][2]); mx3 = fmaxf(s_red[0][3], s_red[1][3]);
    __syncthreads();
    float Aa0 = __expf(La0 - mx0), Aa1 = __expf(La1 - mx1);
    float Aa2 = __expf(La2 - mx2), Aa3 = __expf(La3 - mx3);
    float s0 = Aa0, s1 = Aa1, s2 = Aa2, s3 = Aa3;
    for (int e = 128 + w * 64 + lane; e < dmain; e += 128) {   // cold recompute
        int2 p = csrp[beg + e];
        float4 a = *(const float4*)&as_[p.x * 4];
        float ww = __int_as_float(p.y);
        float v0 = a.x + adv.x + ww * dv.x; v0 = v0 > 0.f ? v0 : 0.2f * v0;
        float v1 = a.y + adv.y + ww * dv.y; v1 = v1 > 0.f ? v1 : 0.2f * v1;
        float v2 = a.z + adv.z + ww * dv.z; v2 = v2 > 0.f ? v2 : 0.2f * v2;
        float v3 = a.w + adv.w + ww * dv.w; v3 = v3 > 0.f ? v3 : 0.2f * v3;
        s0 += __expf(v0 - mx0); s1 += __expf(v1 - mx1);
        s2 += __expf(v2 - mx2); s3 += __expf(v3 - mx3);
    }
    if (degn > CSTR) {
        int oc = *ovf_cnt;
        for (int i = threadIdx.x; i < oc; i += 128) {
            int4 o = ovf[i];
            if (o.x == n) {
                float4 a = *(const float4*)&as_[o.y * 4];
                float ww = __int_as_float(o.z);
                float v0 = a.x + adv.x + ww * dv.x; v0 = v0 > 0.f ? v0 : 0.2f * v0;
                float v1 = a.y + adv.y + ww * dv.y; v1 = v1 > 0.f ? v1 : 0.2f * v1;
                float v2 = a.z + adv.z + ww * dv.z; v2 = v2 > 0.f ? v2 : 0.2f * v2;
                float v3 = a.w + adv.w + ww * dv.w; v3 = v3 > 0.f ? v3 : 0.2f * v3;
                s0 += __expf(v0 - mx0); s1 += __expf(v1 - mx1);
                s2 += __expf(v2 - mx2); s3 += __expf(v3 - mx3);
            }
        }
    }
#pragma unroll
    for (int o = 32; o > 0; o >>= 1) {
        s0 += __shfl_xor(s0, o); s1 += __shfl_xor(s1, o);
        s2 += __shfl_xor(s2, o); s3 += __shfl_xor(s3, o);
    }
    if (lane == 0) {
        s_red[w][0] = s0; s_red[w][1] = s1; s_red[w][2] = s2; s_red[w][3] = s3;
    }
    __syncthreads();
    s0 = s_red[0][0] + s_red[1][0]; s1 = s_red[0][1] + s_red[1][1];
    s2 = s_red[0][2] + s_red[1][2]; s3 = s_red[0][3] + s_red[1][3];
    float inv0 = 1.f / (s0 + 1e-16f), inv1 = 1.f / (s1 + 1e-16f);
    float inv2 = 1.f / (s2 + 1e-16f), inv3 = 1.f / (s3 + 1e-16f);
    // ---- phase B: wave w gathers its own 64 edges; lane owns 8 channels ----
    int hd = lane >> 4;
    const ushort* hbase = hb + 8 * lane;
    float acc0 = 0.f, acc1 = 0.f, acc2 = 0.f, acc3 = 0.f;
    float acc4 = 0.f, acc5 = 0.f, acc6 = 0.f, acc7 = 0.f;
    int mEnd = min(dmain - w * 64, 64);           // may be <=0
#pragma unroll 16
    for (int e = 0; e < mEnd; e++) {
        float r0 = rdlanef(Aa0, e), r1 = rdlanef(Aa1, e);
        float r2 = rdlanef(Aa2, e), r3 = rdlanef(Aa3, e);
        float a = sel4(r0, r1, r2, r3, hd);
        int o = rdlanei(off0, e);
        uint4 v = *(const uint4*)(hbase + o);     // 1KB/wave: full row
        acc0 += a * bflo(v.x); acc1 += a * bfhi(v.x);
        acc2 += a * bflo(v.y); acc3 += a * bfhi(v.y);
        acc4 += a * bflo(v.z); acc5 += a * bfhi(v.z);
        acc6 += a * bflo(v.w); acc7 += a * bfhi(v.w);
    }
    // hoisted per-lane head constants for cold/overflow paths
    float adh = sel4(adv.x, adv.y, adv.z, adv.w, hd);
    float dh  = sel4(dv.x, dv.y, dv.z, dv.w, hd);
    float mxh = sel4(mx0, mx1, mx2, mx3, hd);
    for (int e = 128 + w; e < dmain; e += 2) {    // cold: deg > 128, wave-split
        int2 p = csrp[beg + e];
        float ash = as_[p.x * 4 + hd];
        float ww = __int_as_float(p.y);
        float vv = ash + adh + ww * dh; vv = vv > 0.f ? vv : 0.2f * vv;
        float a = __expf(vv - mxh);
        uint4 v = *(const uint4*)(hbase + p.x * NF);
        acc0 += a * bflo(v.x); acc1 += a * bfhi(v.x);
        acc2 += a * bflo(v.y); acc3 += a * bfhi(v.y);
        acc4 += a * bflo(v.z); acc5 += a * bfhi(v.z);
        acc6 += a * bflo(v.w); acc7 += a * bfhi(v.w);
    }
    if (degn > CSTR) {                            // pathological overflow
        int oc = *ovf_cnt;
        for (int i = w; i < oc; i += 2) {
            int4 o = ovf[i];
            if (o.x == n) {
                float ash = as_[o.y * 4 + hd];
                float ww = __int_as_float(o.z);
                float vv = ash + adh + ww * dh; vv = vv > 0.f ? vv : 0.2f * vv;
                float a = __expf(vv - mxh);
                uint4 v = *(const uint4*)(hbase + o.y * NF);
                acc0 += a * bflo(v.x); acc1 += a * bfhi(v.x);
                acc2 += a * bflo(v.y); acc3 += a * bfhi(v.y);
                acc4 += a * bflo(v.z); acc5 += a * bfhi(v.z);
                acc6 += a * bflo(v.w); acc7 += a * bfhi(v.w);
            }
        }
    }
    // ---- combine the two waves' partials, finalize, fused stats ----
    if (w == 1) {
        s_comb[lane][0] = acc0; s_comb[lane][1] = acc1;
        s_comb[lane][2] = acc2; s_comb[lane][3] = acc3;
        s_comb[lane][4] = acc4; s_comb[lane][5] = acc5;
        s_comb[lane][6] = acc6; s_comb[lane][7] = acc7;
    }
    __syncthreads();
    if (w == 0) {
        acc0 += s_comb[lane][0]; acc1 += s_comb[lane][1];
        acc2 += s_comb[lane][2]; acc3 += s_comb[lane][3];
        acc4 += s_comb[lane][4]; acc5 += s_comb[lane][5];
        acc6 += s_comb[lane][6]; acc7 += s_comb[lane][7];
        float invh = sel4(inv0, inv1, inv2, inv3, hd);
        int ch = 8 * lane;
        float4 b0 = *(const float4*)&bias[ch];
        float4 b1 = *(const float4*)&bias[ch + 4];
        ushort h0 = f2bf(acc0 * invh + b0.x), h1 = f2bf(acc1 * invh + b0.y);
        ushort h2 = f2bf(acc2 * invh + b0.z), h3 = f2bf(acc3 * invh + b0.w);
        ushort h4 = f2bf(acc4 * invh + b1.x), h5 = f2bf(acc5 * invh + b1.y);
        ushort h6 = f2bf(acc6 * invh + b1.z), h7 = f2bf(acc7 * invh + b1.w);
        uint4 ov;
        ov.x = (uint)h0 | ((uint)h1 << 16);
        ov.y = (uint)h2 | ((uint)h3 << 16);
        ov.z = (uint)h4 | ((uint)h5 << 16);
        ov.w = (uint)h6 | ((uint)h7 << 16);
        *(uint4*)&outb[n * NF + ch] = ov;
        // stats partials from the bf16-rounded values (matches k_bnstats numerics)
        float f0 = bf2f(h0), f1 = bf2f(h1), f2 = bf2f(h2), f3 = bf2f(h3);
        float f4 = bf2f(h4), f5 = bf2f(h5), f6 = bf2f(h6), f7 = bf2f(h7);
        s_sum[ch + 0] = f0; s_sq[ch + 0] = f0 * f0;
        s_sum[ch + 1] = f1; s_sq[ch + 1] = f1 * f1;
        s_sum[ch + 2] = f2; s_sq[ch + 2] = f2 * f2;
        s_sum[ch + 3] = f3; s_sq[ch + 3] = f3 * f3;
        s_sum[ch + 4] = f4; s_sq[ch + 4] = f4 * f4;
        s_sum[ch + 5] = f5; s_sq[ch + 5] = f5 * f5;
        s_sum[ch + 6] = f6; s_sq[ch + 6] = f6 * f6;
        s_sum[ch + 7] = f7; s_sq[ch + 7] = f7 * f7;
    }
    __syncthreads();
    // striped atomics: copy = blockIdx&15 (160 RMWs/address); staggered start
    float* st = stats + (blockIdx.x & (NCOPY - 1)) * 1024;
    int c0 = (threadIdx.x * 4 + ((blockIdx.x >> 4) & 7) * 64) & 511;
#pragma unroll
    for (int i = 0; i < 4; i++) {
        int c = c0 + i;
        atomicAdd(&st[c], s_sum[c]);
        atomicAdd(&st[512 + c], s_sq[c]);
    }
}

// ---------------- kernel 4: GEMM2 MFMA + inline BN1+relu + node-att -------
// stats = 16 striped copies (summed here).
__global__ __launch_bounds__(256) void k_gemm2_bn_att(const ushort* __restrict__ Ab,
        const float* __restrict__ stats, const float* __restrict__ g,
        const float* __restrict__ bb, const ushort* __restrict__ BT,
        const float* __restrict__ atts, const float* __restrict__ attd,
        ushort* __restrict__ Cb, float* __restrict__ as_, float* __restrict__ ad_) {
    __shared__ ushort As[64][40];    // [m][k], +8 pad
    __shared__ ushort Bs[128][40];   // [n][k], +8 pad
    __shared__ float s_scale[512], s_shift[512];
    __shared__ float s_ps[2][64], s_pd[2][64];
    int t = threadIdx.x;
    const float invn = 1.0f / (float)NN;
    {
        int j = t;
#pragma unroll
        for (int rep = 0; rep < 2; rep++, j += 256) {
            float su = 0.f, sq = 0.f;
#pragma unroll
            for (int k = 0; k < NCOPY; k++) {
                su += stats[k * 1024 + j];
                sq += stats[k * 1024 + 512 + j];
            }
            float mu = su * invn;
            float var = sq * invn - mu * mu;
            float sc = rsqrtf(var + 1e-5f) * g[j];
            s_scale[j] = sc;
            s_shift[j] = bb[j] - mu * sc;
        }
    }
    int head = blockIdx.x;
    int rowBase = blockIdx.y * 64, colBase = head * 128;
    int w = t >> 6, lane = t & 63;
    int wm = (w >> 1) * 32, wn = (w & 1) * 64;
    int lm = lane & 15, q = lane >> 4;
    f32x4 acc[2][4] = {};
    int sr2 = t >> 2, sk = (t & 3) * 8;
    for (int k0 = 0; k0 < 512; k0 += 32) {
        __syncthreads();
        int jb = k0 + sk;
        float sc[8], sh[8];
#pragma unroll
        for (int c = 0; c < 8; c++) { sc[c] = s_scale[jb + c]; sh[c] = s_shift[jb + c]; }
        uint4 a8 = *(const uint4*)&Ab[(rowBase + sr2) * 512 + jb];   // 8 bf16
        uint4 b0 = *(const uint4*)&BT[(colBase + sr2) * 512 + jb];
        uint4 b1 = *(const uint4*)&BT[(colBase + 64 + sr2) * 512 + jb];
        ushort pa0[8];
        float av[8];
        av[0] = bflo(a8.x); av[1] = bfhi(a8.x); av[2] = bflo(a8.y); av[3] = bfhi(a8.y);
        av[4] = bflo(a8.z); av[5] = bfhi(a8.z); av[6] = bflo(a8.w); av[7] = bfhi(a8.w);
#pragma unroll
        for (int c = 0; c < 8; c++)
            pa0[c] = f2bf(fmaxf(av[c] * sc[c] + sh[c], 0.f));
        *(uint4*)&As[sr2][sk]      = *(uint4*)pa0;
        *(uint4*)&Bs[sr2][sk]      = b0;
        *(uint4*)&Bs[64 + sr2][sk] = b1;
        __syncthreads();
        bf16x8 af[2], bf[4];
#pragma unroll
        for (int i = 0; i < 2; i++) af[i] = *(const bf16x8*)&As[wm + i * 16 + lm][q * 8];
#pragma unroll
        for (int j = 0; j < 4; j++) bf[j] = *(const bf16x8*)&Bs[wn + j * 16 + lm][q * 8];
#pragma unroll
        for (int i = 0; i < 2; i++)
#pragma unroll
            for (int j = 0; j < 4; j++)
                acc[i][j] = __builtin_amdgcn_mfma_f32_16x16x32_bf16(af[i], bf[j], acc[i][j], 0, 0, 0);
    }
    // C store (bf16)
#pragma unroll
    for (int i = 0; i < 2; i++) {
        int row = rowBase + wm + i * 16 + q * 4;
#pragma unroll
        for (int j = 0; j < 4; j++) {
            int col = colBase + wn + j * 16 + lm;
#pragma unroll
            for (int r = 0; r < 4; r++)
                Cb[(row + r) * 512 + col] = f2bf(acc[i][j][r]);
        }
    }
    // node-att epilogue: head dot for this block's 64 rows
    float sa[4], da[4];
#pragma unroll
    for (int j = 0; j < 4; j++) {
        int col = colBase + wn + j * 16 + lm;
        sa[j] = atts[col]; da[j] = attd[col];
    }
#pragma unroll
    for (int i = 0; i < 2; i++) {
#pragma unroll
        for (int r = 0; r < 4; r++) {
            float ps = 0.f, pd = 0.f;
#pragma unroll
            for (int j = 0; j < 4; j++) {
                float c = acc[i][j][r];
                ps += c * sa[j]; pd += c * da[j];
            }
#pragma unroll
            for (int o = 1; o < 16; o <<= 1) { ps += __shfl_xor(ps, o); pd += __shfl_xor(pd, o); }
            if (lm == 0) {
                int row = wm + i * 16 + q * 4 + r;
                s_ps[w & 1][row] = ps; s_pd[w & 1][row] = pd;
            }
        }
    }
    __syncthreads();
    if (t < 64) {
        as_[(rowBase + t) * 4 + head] = s_ps[0][t] + s_ps[1][t];
    } else if (t < 128) {
        int row = t - 64;
        ad_[(rowBase + row) * 4 + head] = s_pd[0][row] + s_pd[1][row];
    }
}

// ---------------- kernel 5: FC MFMA + inline BN2+relu + mask + adj --------
// stats = 16 striped copies (summed here).
__global__ __launch_bounds__(256) void k_fc_bn(const ushort* __restrict__ e2b,
        const float* __restrict__ stats, const float* __restrict__ g,
        const float* __restrict__ bb, const ushort* __restrict__ WfcT,
        const float* __restrict__ bfc, const int* __restrict__ mask,
        const float* __restrict__ adj, float* __restrict__ out) {
    __shared__ float s_scale[512], s_shift[512];
    __shared__ f32x4 s_acc[3][64][3];   // [wave-1][lane][jt]
    int t = threadIdx.x;
    int w = t >> 6, lane = t & 63;
    const float invn = 1.0f / (float)NN;
#pragma unroll
    for (int j = t; j < 512; j += 256) {
        float su = 0.f, sq = 0.f;
#pragma unroll
        for (int k = 0; k < NCOPY; k++) {
            su += stats[k * 1024 + j];
            sq += stats[k * 1024 + 512 + j];
        }
        float mu = su * invn;
        float var = sq * invn - mu * mu;
        float sc = rsqrtf(var + 1e-5f) * g[j];
        s_scale[j] = sc;
        s_shift[j] = bb[j] - mu * sc;
    }
    __syncthreads();
    int r0 = blockIdx.x * 16;
    int lm = lane & 15, q = lane >> 4;
    f32x4 acc[3] = {};
#pragma unroll
    for (int kk = 0; kk < 4; kk++) {
        int k0 = w * 128 + kk * 32;
        int jb = k0 + q * 8;
        uint4 a8 = *(const uint4*)&e2b[(r0 + lm) * 512 + jb];
        float av[8];
        av[0] = bflo(a8.x); av[1] = bfhi(a8.x); av[2] = bflo(a8.y); av[3] = bfhi(a8.y);
        av[4] = bflo(a8.z); av[5] = bfhi(a8.z); av[6] = bflo(a8.w); av[7] = bfhi(a8.w);
        ushort pa[8];
#pragma unroll
        for (int c = 0; c < 8; c++)
            pa[c] = f2bf(fmaxf(av[c] * s_scale[jb + c] + s_shift[jb + c], 0.f));
        bf16x8 af = *(const bf16x8*)pa;
#pragma unroll
        for (int jt = 0; jt < 3; jt++) {
            bf16x8 bf = *(const bf16x8*)&WfcT[(jt * 16 + lm) * 512 + k0 + q * 8];
            acc[jt] = __builtin_amdgcn_mfma_f32_16x16x32_bf16(af, bf, acc[jt], 0, 0, 0);
        }
    }
    if (w > 0) {
#pragma unroll
        for (int jt = 0; jt < 3; jt++) s_acc[w - 1][lane][jt] = acc[jt];
    }
    __syncthreads();
    if (w == 0) {
#pragma unroll
        for (int jt = 0; jt < 3; jt++) {
            acc[jt] += s_acc[0][lane][jt] + s_acc[1][lane][jt] + s_acc[2][lane][jt];
            int col = jt * 16 + lm;
            if (col < OUTE) {
#pragma unroll
                for (int r = 0; r < 4; r++) {
                    int n = r0 + q * 4 + r;
                    float v = acc[jt][r] + bfc[col];
                    v = mask[n] ? v : 0.f;
                    out[n * OUTE + col] = v + adj[n * OUTE + col];
                }
            }
        }
    }
}

// ---------------- host side ----------------------------------------------
extern "C" void kernel_launch(void* const* d_in, const int* in_sizes, int n_in,
                              void* d_out, int out_size, void* d_ws, size_t ws_size,
                              hipStream_t stream) {
    const float* x       = (const float*)d_in[0];
    const int*   ei      = (const int*)d_in[1];
    const float* pos     = (const float*)d_in[2];
    const int*   mask    = (const int*)d_in[3];
    const float* adj     = (const float*)d_in[4];
    const float* W1      = (const float*)d_in[5];
    const float* atts1   = (const float*)d_in[6];
    const float* attd1   = (const float*)d_in[7];
    const float* We1     = (const float*)d_in[8];
    const float* atte1   = (const float*)d_in[9];
    const float* bias1   = (const float*)d_in[10];
    const float* g1      = (const float*)d_in[11];
    const float* be1     = (const float*)d_in[12];
    const float* W2      = (const float*)d_in[13];
    const float* atts2   = (const float*)d_in[14];
    const float* attd2   = (const float*)d_in[15];
    const float* We2     = (const float*)d_in[16];
    const float* atte2   = (const float*)d_in[17];
    const float* bias2   = (const float*)d_in[18];
    const float* g2      = (const float*)d_in[19];
    const float* be2     = (const float*)d_in[20];
    const float* Wfc     = (const float*)d_in[21];
    const float* bfc     = (const float*)d_in[22];
    float* out = (float*)d_out;

    // workspace layout (int-element offsets; 16B-aligned blocks)
    char* ws = (char*)d_ws;
    int*    deg     = (int*)(ws);                       // 2560
    int*    ovf_cnt = (int*)(ws + 2560 * 4);            // 1 (pad to 2576)
    float*  st16_1  = (float*)(ws + 2576 * 4);          // 16*1024 = 16384
    float*  st16_2  = (float*)(ws + 18960 * 4);         // 16384
    // ---- zero region = first 35344 ints ----
    float*  dote    = (float*)(ws + 35344 * 4);         // 8 (pad 16)
    int2*   csrp    = (int2*)(ws + 35360 * 4);          // 2560*256 int2 = 1310720 ints
    int4*   ovf     = (int4*)(ws + 1346080 * 4);        // 16384 int4 = 65536 ints
    float*  as_     = (float*)(ws + 1411616 * 4);       // 10240
    float*  ad_     = (float*)(ws + 1421856 * 4);       // 10240
    ushort* t1b     = (ushort*)(ws + 1432096 * 4);      // 1310720 bf16 = 655360 ints
    ushort* hb      = (ushort*)(ws + 2087456 * 4);      // 1310720 bf16 = 655360 ints
    ushort* W2T     = (ushort*)(ws + 2742816 * 4);      // 262144 bf16 = 131072 ints
    ushort* WfcT    = (ushort*)(ws + 2873888 * 4);      // 24576 bf16 = 12288 ints
    // total ~2.89M ints = ~11.5 MB

    hipMemsetAsync(d_ws, 0, 35344 * 4, stream);

    // CSR fill (single-pass) + weight prep + GEMM1+att (4 nodes/block)
    k_csr_gemm1<<<802 + NN / 4, 256, 0, stream>>>(ei, pos, deg, csrp, ovf_cnt, ovf,
                                                  We1, atte1, We2, atte2, dote,
                                                  Wfc, WfcT, W2, W2T,
                                                  x, W1, atts1, attd1, hb, as_, ad_);

    // ---- layer 1 (BN-stats fused, striped x16) ----
    k_edge_agg<<<NN, 128, 0, stream>>>(deg, csrp, ovf_cnt, ovf, as_, ad_,
                                       dote, hb, bias1, t1b, st16_1);

    // ---- layer 2 (BN1 inline in GEMM2 A-staging; node-att in epilogue) ----
    k_gemm2_bn_att<<<dim3(4, NN / 64), 256, 0, stream>>>(t1b, st16_1, g1, be1, W2T,
                                                         atts2, attd2, hb, as_, ad_);
    k_edge_agg<<<NN, 128, 0, stream>>>(deg, csrp, ovf_cnt, ovf, as_, ad_,
                                       dote + 4, hb, bias2, t1b, st16_2);

    // ---- head (BN2 inline in FC A-fragment load) ----
    k_fc_bn<<<NN / 16, 256, 0, stream>>>(t1b, st16_2, g2, be2, WfcT, bfc, mask, adj, out);
}

// Round 6
// 195.993 us; speedup vs baseline: 1.3515x; 1.3515x over previous
//
#include <hip/hip_runtime.h>
#include <hip/hip_bf16.h>

#define NN 2560        // nodes
#define NE 163840      // edges
#define NH 4           // heads
#define NC 128         // channels per head
#define NF 512         // NH*NC
#define OUTE 40
#define CSTR 256       // fixed CSR stride per node; deg>CSTR -> overflow list

typedef short bf16x8 __attribute__((ext_vector_type(8)));
typedef float f32x4 __attribute__((ext_vector_type(4)));

__device__ inline ushort f2bf(float f) {
    uint u = __float_as_uint(f);
    uint r = u + 0x7FFF + ((u >> 16) & 1);   // round-to-nearest-even
    return (ushort)(r >> 16);
}
__device__ inline float bflo(uint v) { return __uint_as_float(v << 16); }
__device__ inline float bfhi(uint v) { return __uint_as_float(v & 0xFFFF0000u); }
__device__ inline float bf2f(ushort u) { return __uint_as_float(((uint)u) << 16); }
__device__ inline float rdlanef(float v, int l) {
    return __int_as_float(__builtin_amdgcn_readlane(__float_as_int(v), l));
}
__device__ inline int rdlanei(int v, int l) {
    return __builtin_amdgcn_readlane(v, l);
}
// 4-way select by per-lane-constant head index (3 cndmask, masks hoisted)
__device__ inline float sel4(float r0, float r1, float r2, float r3, int hd) {
    return (hd & 2) ? ((hd & 1) ? r3 : r2) : ((hd & 1) ? r1 : r0);
}

// ---------------- kernel 1: CSR fill (single-pass) + dote/WfcT/W2T + GEMM1+att
__global__ __launch_bounds__(256) void k_csr_gemm1(const int* __restrict__ ei,
        const float* __restrict__ pos, int* __restrict__ deg,
        int2* __restrict__ csrp, int* __restrict__ ovf_cnt, int4* __restrict__ ovf,
        const float* __restrict__ We1, const float* __restrict__ ae1,
        const float* __restrict__ We2, const float* __restrict__ ae2,
        float* __restrict__ dote,
        const float* __restrict__ Wfc, ushort* __restrict__ WfcT,
        const float* __restrict__ W2, ushort* __restrict__ W2T,
        const float* __restrict__ x, const float* __restrict__ W1,
        const float* __restrict__ atts, const float* __restrict__ attd,
        ushort* __restrict__ hb, float* __restrict__ as_, float* __restrict__ ad_) {
    __shared__ ushort tile[64][72];
    __shared__ float s_x[4][32];
    __shared__ float4 s_red[4][4];     // [wave][node]
    int b = blockIdx.x;
    if (b < 640) {
        int e = b * 256 + threadIdx.x;
        int s = ei[e], d = ei[NE + e];
        float dx = pos[2 * s] - pos[2 * d];
        float dy = pos[2 * s + 1] - pos[2 * d + 1];
        float w = 1.0f / (sqrtf(dx * dx + dy * dy) + 1e-6f);
        int r = atomicAdd(&deg[d], 1);     // slot + degree in one pass
        if (r < CSTR) {
            csrp[(d << 8) + r] = make_int2(s, __float_as_int(w));
        } else {                            // pathological deg > CSTR: exact fallback
            int i = atomicAdd(ovf_cnt, 1);
            ovf[i] = make_int4(d, s, __float_as_int(w), 0);
        }
        return;
    }
    if (b < 642) {
        int t = threadIdx.x;
        const float* W = (b == 641) ? We2 : We1;
        const float* A = (b == 641) ? ae2 : ae1;
        int w = t >> 6, l = t & 63;
        float p = W[w * 128 + l] * A[w * 128 + l] + W[w * 128 + 64 + l] * A[w * 128 + 64 + l];
#pragma unroll
        for (int o = 32; o > 0; o >>= 1) p += __shfl_down(p, o);
        if (l == 0) dote[(b - 640) * 4 + w] = p;
        return;
    }
    if (b < 738) {
        int idx = (b - 642) * 256 + threadIdx.x;    // j*512 + k
        int j = idx >> 9, k = idx & 511;
        WfcT[idx] = (j < OUTE) ? f2bf(Wfc[k * OUTE + j]) : (ushort)0;
        return;
    }
    if (b < 802) {
        int id = b - 738;
        int n0 = (id & 7) * 64, k0 = (id >> 3) * 64;
        int t = threadIdx.x;
        int r = t >> 2, cseg = (t & 3) * 16;
#pragma unroll
        for (int c = 0; c < 16; c += 4) {
            float4 v = *(const float4*)&W2[(k0 + r) * 512 + n0 + cseg + c];
            tile[cseg + c + 0][r] = f2bf(v.x);
            tile[cseg + c + 1][r] = f2bf(v.y);
            tile[cseg + c + 2][r] = f2bf(v.z);
            tile[cseg + c + 3][r] = f2bf(v.w);
        }
        __syncthreads();
        *(uint4*)&W2T[(n0 + r) * 512 + k0 + cseg]     = *(uint4*)&tile[r][cseg];
        *(uint4*)&W2T[(n0 + r) * 512 + k0 + cseg + 8] = *(uint4*)&tile[r][cseg + 8];
        return;
    }
    int n0 = (b - 802) * 4, t = threadIdx.x;
    if (t < 128) s_x[t >> 5][t & 31] = x[n0 * 32 + t];
    __syncthreads();
    float a0[4] = {0.f, 0.f, 0.f, 0.f}, a1[4] = {0.f, 0.f, 0.f, 0.f};
#pragma unroll
    for (int k = 0; k < 32; k++) {
        float w0 = W1[k * 512 + t];
        float w1 = W1[k * 512 + t + 256];
#pragma unroll
        for (int nn = 0; nn < 4; nn++) {
            a0[nn] += s_x[nn][k] * w0;
            a1[nn] += s_x[nn][k] * w1;
        }
    }
    float sa0 = atts[t], sa1 = atts[t + 256];
    float da0 = attd[t], da1 = attd[t + 256];
    int w = t >> 6, lane = t & 63;
#pragma unroll
    for (int nn = 0; nn < 4; nn++) {
        hb[(n0 + nn) * 512 + t] = f2bf(a0[nn]);
        hb[(n0 + nn) * 512 + t + 256] = f2bf(a1[nn]);
        float ps0 = a0[nn] * sa0, pd0 = a0[nn] * da0;
        float ps1 = a1[nn] * sa1, pd1 = a1[nn] * da1;
#pragma unroll
        for (int o = 32; o > 0; o >>= 1) {
            ps0 += __shfl_xor(ps0, o); pd0 += __shfl_xor(pd0, o);
            ps1 += __shfl_xor(ps1, o); pd1 += __shfl_xor(pd1, o);
        }
        if (lane == 0) s_red[w][nn] = make_float4(ps0, pd0, ps1, pd1);
    }
    __syncthreads();
    if (t < 4) {
        int nn = t, n = n0 + nn;
        float4 r0 = s_red[0][nn], r1 = s_red[1][nn], r2 = s_red[2][nn], r3 = s_red[3][nn];
        as_[n * 4 + 0] = r0.x + r1.x; as_[n * 4 + 1] = r2.x + r3.x;
        as_[n * 4 + 2] = r0.z + r1.z; as_[n * 4 + 3] = r2.z + r3.z;
        ad_[n * 4 + 0] = r0.y + r1.y; ad_[n * 4 + 1] = r2.y + r3.y;
        ad_[n * 4 + 2] = r0.w + r1.w; ad_[n * 4 + 3] = r2.w + r3.w;
    }
}

// ---------------- kernel 2: softmax+agg, wave = node (all 4 heads) ---------
// R26: identical to R24 (204.4us baseline) except phase B uses explicit 8-deep
// load batching: 8 wave-uniform addresses + 8 independent uint4 row-loads
// issued before any FMA consumes them. All edge-agg variants (R21/R24/R25)
// measured ~26us because the compiler kept only 1-2 gathers in flight
// (VGPR_Count=24); this forces ~8/wave (~20/SIMD at 2.5 waves/SIMD).
__global__ __launch_bounds__(128) void k_edge_agg(const int* __restrict__ deg_,
        const int2* __restrict__ csrp, const int* __restrict__ ovf_cnt,
        const int4* __restrict__ ovf, const float* __restrict__ as_,
        const float* __restrict__ ad_, const float* __restrict__ dote,
        const ushort* __restrict__ hb, const float* __restrict__ bias,
        ushort* __restrict__ outb) {
    int w = threadIdx.x >> 6, lane = threadIdx.x & 63;
    int n = blockIdx.x * 2 + w;
    int beg = n << 8;
    int degn = deg_[n];
    int dmain = min(degn, CSTR);
    float4 adv = *(const float4*)&ad_[n * 4];
    float4 dv  = *(const float4*)dote;
    // ---- phase A: softmax for all 4 heads in registers ----
    float La0 = -1e30f, La1 = -1e30f, La2 = -1e30f, La3 = -1e30f;
    float Lb0 = -1e30f, Lb1 = -1e30f, Lb2 = -1e30f, Lb3 = -1e30f;
    int off0 = 0, off1 = 0;
    if (lane < dmain) {
        int2 p = csrp[beg + lane];
        off0 = p.x * NF;
        float4 a = *(const float4*)&as_[p.x * 4];
        float ww = __int_as_float(p.y);
        float v0 = a.x + adv.x + ww * dv.x; La0 = v0 > 0.f ? v0 : 0.2f * v0;
        float v1 = a.y + adv.y + ww * dv.y; La1 = v1 > 0.f ? v1 : 0.2f * v1;
        float v2 = a.z + adv.z + ww * dv.z; La2 = v2 > 0.f ? v2 : 0.2f * v2;
        float v3 = a.w + adv.w + ww * dv.w; La3 = v3 > 0.f ? v3 : 0.2f * v3;
    }
    if (lane + 64 < dmain) {
        int2 p = csrp[beg + lane + 64];
        off1 = p.x * NF;
        float4 a = *(const float4*)&as_[p.x * 4];
        float ww = __int_as_float(p.y);
        float v0 = a.x + adv.x + ww * dv.x; Lb0 = v0 > 0.f ? v0 : 0.2f * v0;
        float v1 = a.y + adv.y + ww * dv.y; Lb1 = v1 > 0.f ? v1 : 0.2f * v1;
        float v2 = a.z + adv.z + ww * dv.z; Lb2 = v2 > 0.f ? v2 : 0.2f * v2;
        float v3 = a.w + adv.w + ww * dv.w; Lb3 = v3 > 0.f ? v3 : 0.2f * v3;
    }
    float mx0 = fmaxf(La0, Lb0), mx1 = fmaxf(La1, Lb1);
    float mx2 = fmaxf(La2, Lb2), mx3 = fmaxf(La3, Lb3);
    for (int e = 128 + lane; e < dmain; e += 64) {        // cold: deg > 128
        int2 p = csrp[beg + e];
        float4 a = *(const float4*)&as_[p.x * 4];
        float ww = __int_as_float(p.y);
        float v0 = a.x + adv.x + ww * dv.x; v0 = v0 > 0.f ? v0 : 0.2f * v0;
        float v1 = a.y + adv.y + ww * dv.y; v1 = v1 > 0.f ? v1 : 0.2f * v1;
        float v2 = a.z + adv.z + ww * dv.z; v2 = v2 > 0.f ? v2 : 0.2f * v2;
        float v3 = a.w + adv.w + ww * dv.w; v3 = v3 > 0.f ? v3 : 0.2f * v3;
        mx0 = fmaxf(mx0, v0); mx1 = fmaxf(mx1, v1);
        mx2 = fmaxf(mx2, v2); mx3 = fmaxf(mx3, v3);
    }
    if (degn > CSTR) {                                    // pathological overflow
        int oc = *ovf_cnt;
        for (int i = lane; i < oc; i += 64) {
            int4 o = ovf[i];
            if (o.x == n) {
                float4 a = *(const float4*)&as_[o.y * 4];
                float ww = __int_as_float(o.z);
                float v0 = a.x + adv.x + ww * dv.x; v0 = v0 > 0.f ? v0 : 0.2f * v0;
                float v1 = a.y + adv.y + ww * dv.y; v1 = v1 > 0.f ? v1 : 0.2f * v1;
                float v2 = a.z + adv.z + ww * dv.z; v2 = v2 > 0.f ? v2 : 0.2f * v2;
                float v3 = a.w + adv.w + ww * dv.w; v3 = v3 > 0.f ? v3 : 0.2f * v3;
                mx0 = fmaxf(mx0, v0); mx1 = fmaxf(mx1, v1);
                mx2 = fmaxf(mx2, v2); mx3 = fmaxf(mx3, v3);
            }
        }
    }
#pragma unroll
    for (int o = 32; o > 0; o >>= 1) {
        mx0 = fmaxf(mx0, __shfl_xor(mx0, o));
        mx1 = fmaxf(mx1, __shfl_xor(mx1, o));
        mx2 = fmaxf(mx2, __shfl_xor(mx2, o));
        mx3 = fmaxf(mx3, __shfl_xor(mx3, o));
    }
    float Aa0 = __expf(La0 - mx0), Aa1 = __expf(La1 - mx1);
    float Aa2 = __expf(La2 - mx2), Aa3 = __expf(La3 - mx3);
    float Ab0 = __expf(Lb0 - mx0), Ab1 = __expf(Lb1 - mx1);
    float Ab2 = __expf(Lb2 - mx2), Ab3 = __expf(Lb3 - mx3);
    float s0 = Aa0 + Ab0, s1 = Aa1 + Ab1, s2 = Aa2 + Ab2, s3 = Aa3 + Ab3;
    for (int e = 128 + lane; e < dmain; e += 64) {        // cold recompute
        int2 p = csrp[beg + e];
        float4 a = *(const float4*)&as_[p.x * 4];
        float ww = __int_as_float(p.y);
        float v0 = a.x + adv.x + ww * dv.x; v0 = v0 > 0.f ? v0 : 0.2f * v0;
        float v1 = a.y + adv.y + ww * dv.y; v1 = v1 > 0.f ? v1 : 0.2f * v1;
        float v2 = a.z + adv.z + ww * dv.z; v2 = v2 > 0.f ? v2 : 0.2f * v2;
        float v3 = a.w + adv.w + ww * dv.w; v3 = v3 > 0.f ? v3 : 0.2f * v3;
        s0 += __expf(v0 - mx0); s1 += __expf(v1 - mx1);
        s2 += __expf(v2 - mx2); s3 += __expf(v3 - mx3);
    }
    if (degn > CSTR) {
        int oc = *ovf_cnt;
        for (int i = lane; i < oc; i += 64) {
            int4 o = ovf[i];
            if (o.x == n) {
                float4 a = *(const float4*)&as_[o.y * 4];
                float ww = __int_as_float(o.z);
                float v0 = a.x + adv.x + ww * dv.x; v0 = v0 > 0.f ? v0 : 0.2f * v0;
                float v1 = a.y + adv.y + ww * dv.y; v1 = v1 > 0.f ? v1 : 0.2f * v1;
                float v2 = a.z + adv.z + ww * dv.z; v2 = v2 > 0.f ? v2 : 0.2f * v2;
                float v3 = a.w + adv.w + ww * dv.w; v3 = v3 > 0.f ? v3 : 0.2f * v3;
                s0 += __expf(v0 - mx0); s1 += __expf(v1 - mx1);
                s2 += __expf(v2 - mx2); s3 += __expf(v3 - mx3);
            }
        }
    }
#pragma unroll
    for (int o = 32; o > 0; o >>= 1) {
        s0 += __shfl_xor(s0, o); s1 += __shfl_xor(s1, o);
        s2 += __shfl_xor(s2, o); s3 += __shfl_xor(s3, o);
    }
    float inv0 = 1.f / (s0 + 1e-16f), inv1 = 1.f / (s1 + 1e-16f);
    float inv2 = 1.f / (s2 + 1e-16f), inv3 = 1.f / (s3 + 1e-16f);
    // ---- phase B: lane owns 8 channels at 8*lane; head = lane>>4 ----
    int hd = lane >> 4;
    const ushort* hbase = hb + 8 * lane;
    float acc0 = 0.f, acc1 = 0.f, acc2 = 0.f, acc3 = 0.f;
    float acc4 = 0.f, acc5 = 0.f, acc6 = 0.f, acc7 = 0.f;
    int m0 = min(dmain, 64);
    int e = 0;
    for (; e + 8 <= m0; e += 8) {                 // 8-deep batched gathers
        int o[8]; float aa[8];
#pragma unroll
        for (int j = 0; j < 8; j++) {
            o[j] = rdlanei(off0, e + j);
            float r0 = rdlanef(Aa0, e + j), r1 = rdlanef(Aa1, e + j);
            float r2 = rdlanef(Aa2, e + j), r3 = rdlanef(Aa3, e + j);
            aa[j] = sel4(r0, r1, r2, r3, hd);
        }
        uint4 v[8];
#pragma unroll
        for (int j = 0; j < 8; j++) v[j] = *(const uint4*)(hbase + o[j]);
#pragma unroll
        for (int j = 0; j < 8; j++) {
            acc0 += aa[j] * bflo(v[j].x); acc1 += aa[j] * bfhi(v[j].x);
            acc2 += aa[j] * bflo(v[j].y); acc3 += aa[j] * bfhi(v[j].y);
            acc4 += aa[j] * bflo(v[j].z); acc5 += aa[j] * bfhi(v[j].z);
            acc6 += aa[j] * bflo(v[j].w); acc7 += aa[j] * bfhi(v[j].w);
        }
    }
    for (; e < m0; e++) {                         // tail (deg not multiple of 8)
        float r0 = rdlanef(Aa0, e), r1 = rdlanef(Aa1, e);
        float r2 = rdlanef(Aa2, e), r3 = rdlanef(Aa3, e);
        float a = sel4(r0, r1, r2, r3, hd);
        int o = rdlanei(off0, e);
        uint4 v = *(const uint4*)(hbase + o);
        acc0 += a * bflo(v.x); acc1 += a * bfhi(v.x);
        acc2 += a * bflo(v.y); acc3 += a * bfhi(v.y);
        acc4 += a * bflo(v.z); acc5 += a * bfhi(v.z);
        acc6 += a * bflo(v.w); acc7 += a * bfhi(v.w);
    }
    int m1b = max(min(dmain, 128) - 64, 0);       // segment 2 length
    e = 0;
    for (; e + 8 <= m1b; e += 8) {
        int o[8]; float aa[8];
#pragma unroll
        for (int j = 0; j < 8; j++) {
            o[j] = rdlanei(off1, e + j);
            float r0 = rdlanef(Ab0, e + j), r1 = rdlanef(Ab1, e + j);
            float r2 = rdlanef(Ab2, e + j), r3 = rdlanef(Ab3, e + j);
            aa[j] = sel4(r0, r1, r2, r3, hd);
        }
        uint4 v[8];
#pragma unroll
        for (int j = 0; j < 8; j++) v[j] = *(const uint4*)(hbase + o[j]);
#pragma unroll
        for (int j = 0; j < 8; j++) {
            acc0 += aa[j] * bflo(v[j].x); acc1 += aa[j] * bfhi(v[j].x);
            acc2 += aa[j] * bflo(v[j].y); acc3 += aa[j] * bfhi(v[j].y);
            acc4 += aa[j] * bflo(v[j].z); acc5 += aa[j] * bfhi(v[j].z);
            acc6 += aa[j] * bflo(v[j].w); acc7 += aa[j] * bfhi(v[j].w);
        }
    }
    for (; e < m1b; e++) {
        float r0 = rdlanef(Ab0, e), r1 = rdlanef(Ab1, e);
        float r2 = rdlanef(Ab2, e), r3 = rdlanef(Ab3, e);
        float a = sel4(r0, r1, r2, r3, hd);
        int o = rdlanei(off1, e);
        uint4 v = *(const uint4*)(hbase + o);
        acc0 += a * bflo(v.x); acc1 += a * bfhi(v.x);
        acc2 += a * bflo(v.y); acc3 += a * bfhi(v.y);
        acc4 += a * bflo(v.z); acc5 += a * bfhi(v.z);
        acc6 += a * bflo(v.w); acc7 += a * bfhi(v.w);
    }
    // hoisted per-lane head constants for cold/overflow paths
    float adh = sel4(adv.x, adv.y, adv.z, adv.w, hd);
    float dh  = sel4(dv.x, dv.y, dv.z, dv.w, hd);
    float mxh = sel4(mx0, mx1, mx2, mx3, hd);
    for (int ee = 128; ee < dmain; ee++) {                // cold: deg > 128
        int2 p = csrp[beg + ee];
        float ash = as_[p.x * 4 + hd];
        float ww = __int_as_float(p.y);
        float vv = ash + adh + ww * dh; vv = vv > 0.f ? vv : 0.2f * vv;
        float a = __expf(vv - mxh);
        uint4 v = *(const uint4*)(hbase + p.x * NF);
        acc0 += a * bflo(v.x); acc1 += a * bfhi(v.x);
        acc2 += a * bflo(v.y); acc3 += a * bfhi(v.y);
        acc4 += a * bflo(v.z); acc5 += a * bfhi(v.z);
        acc6 += a * bflo(v.w); acc7 += a * bfhi(v.w);
    }
    if (degn > CSTR) {                                    // pathological overflow
        int oc = *ovf_cnt;
        for (int i = 0; i < oc; i++) {
            int4 o = ovf[i];
            if (o.x == n) {
                float ash = as_[o.y * 4 + hd];
                float ww = __int_as_float(o.z);
                float vv = ash + adh + ww * dh; vv = vv > 0.f ? vv : 0.2f * vv;
                float a = __expf(vv - mxh);
                uint4 v = *(const uint4*)(hbase + o.y * NF);
                acc0 += a * bflo(v.x); acc1 += a * bfhi(v.x);
                acc2 += a * bflo(v.y); acc3 += a * bfhi(v.y);
                acc4 += a * bflo(v.z); acc5 += a * bfhi(v.z);
                acc6 += a * bflo(v.w); acc7 += a * bfhi(v.w);
            }
        }
    }
    float invh = sel4(inv0, inv1, inv2, inv3, hd);
    int ch = 8 * lane;
    float4 b0 = *(const float4*)&bias[ch];
    float4 b1 = *(const float4*)&bias[ch + 4];
    uint4 ov;
    ov.x = (uint)f2bf(acc0 * invh + b0.x) | ((uint)f2bf(acc1 * invh + b0.y) << 16);
    ov.y = (uint)f2bf(acc2 * invh + b0.z) | ((uint)f2bf(acc3 * invh + b0.w) << 16);
    ov.z = (uint)f2bf(acc4 * invh + b1.x) | ((uint)f2bf(acc5 * invh + b1.y) << 16);
    ov.w = (uint)f2bf(acc6 * invh + b1.z) | ((uint)f2bf(acc7 * invh + b1.w) << 16);
    *(uint4*)&outb[n * NF + ch] = ov;
}

// ---------------- kernel 3: BN stats (160 blocks, uint4 loads) -------------
__global__ __launch_bounds__(256) void k_bnstats(const ushort* __restrict__ xs,
        float* __restrict__ stats) {
    __shared__ float ps[2048];           // [4][512]
    __shared__ float pq[2048];
    int t = threadIdx.x;
    int c8 = (t & 63) * 8, rr = t >> 6;
    float s[8] = {0.f,0.f,0.f,0.f,0.f,0.f,0.f,0.f};
    float q[8] = {0.f,0.f,0.f,0.f,0.f,0.f,0.f,0.f};
#pragma unroll
    for (int rj = 0; rj < 4; rj++) {
        int r = blockIdx.x * 16 + rr * 4 + rj;
        uint4 v = *(const uint4*)&xs[r * NF + c8];
        float vv[8];
        vv[0] = bflo(v.x); vv[1] = bfhi(v.x); vv[2] = bflo(v.y); vv[3] = bfhi(v.y);
        vv[4] = bflo(v.z); vv[5] = bfhi(v.z); vv[6] = bflo(v.w); vv[7] = bfhi(v.w);
#pragma unroll
        for (int c = 0; c < 8; c++) { s[c] += vv[c]; q[c] += vv[c] * vv[c]; }
    }
#pragma unroll
    for (int c = 0; c < 8; c++) {
        ps[rr * 512 + c8 + c] = s[c];
        pq[rr * 512 + c8 + c] = q[c];
    }
    __syncthreads();
    for (int ch = t; ch < 512; ch += 256) {
        atomicAdd(&stats[ch], ps[ch] + ps[512 + ch] + ps[1024 + ch] + ps[1536 + ch]);
        atomicAdd(&stats[NF + ch], pq[ch] + pq[512 + ch] + pq[1024 + ch] + pq[1536 + ch]);
    }
}

// ---------------- kernel 4: GEMM2 MFMA + inline BN1+relu + node-att -------
__global__ __launch_bounds__(256) void k_gemm2_bn_att(const ushort* __restrict__ Ab,
        const float* __restrict__ stats, const float* __restrict__ g,
        const float* __restrict__ bb, const ushort* __restrict__ BT,
        const float* __restrict__ atts, const float* __restrict__ attd,
        ushort* __restrict__ Cb, float* __restrict__ as_, float* __restrict__ ad_) {
    __shared__ ushort As[64][40];    // [m][k], +8 pad
    __shared__ ushort Bs[128][40];   // [n][k], +8 pad
    __shared__ float s_scale[512], s_shift[512];
    __shared__ float s_ps[2][64], s_pd[2][64];
    int t = threadIdx.x;
    const float invn = 1.0f / (float)NN;
    {
        int j = t;
#pragma unroll
        for (int rep = 0; rep < 2; rep++, j += 256) {
            float mu = stats[j] * invn;
            float var = stats[NF + j] * invn - mu * mu;
            float sc = rsqrtf(var + 1e-5f) * g[j];
            s_scale[j] = sc;
            s_shift[j] = bb[j] - mu * sc;
        }
    }
    int head = blockIdx.x;
    int rowBase = blockIdx.y * 64, colBase = head * 128;
    int w = t >> 6, lane = t & 63;
    int wm = (w >> 1) * 32, wn = (w & 1) * 64;
    int lm = lane & 15, q = lane >> 4;
    f32x4 acc[2][4] = {};
    int sr2 = t >> 2, sk = (t & 3) * 8;
    for (int k0 = 0; k0 < 512; k0 += 32) {
        __syncthreads();
        int jb = k0 + sk;
        float sc[8], sh[8];
#pragma unroll
        for (int c = 0; c < 8; c++) { sc[c] = s_scale[jb + c]; sh[c] = s_shift[jb + c]; }
        uint4 a8 = *(const uint4*)&Ab[(rowBase + sr2) * 512 + jb];   // 8 bf16
        uint4 b0 = *(const uint4*)&BT[(colBase + sr2) * 512 + jb];
        uint4 b1 = *(const uint4*)&BT[(colBase + 64 + sr2) * 512 + jb];
        ushort pa0[8];
        float av[8];
        av[0] = bflo(a8.x); av[1] = bfhi(a8.x); av[2] = bflo(a8.y); av[3] = bfhi(a8.y);
        av[4] = bflo(a8.z); av[5] = bfhi(a8.z); av[6] = bflo(a8.w); av[7] = bfhi(a8.w);
#pragma unroll
        for (int c = 0; c < 8; c++)
            pa0[c] = f2bf(fmaxf(av[c] * sc[c] + sh[c], 0.f));
        *(uint4*)&As[sr2][sk]      = *(uint4*)pa0;
        *(uint4*)&Bs[sr2][sk]      = b0;
        *(uint4*)&Bs[64 + sr2][sk] = b1;
        __syncthreads();
        bf16x8 af[2], bf[4];
#pragma unroll
        for (int i = 0; i < 2; i++) af[i] = *(const bf16x8*)&As[wm + i * 16 + lm][q * 8];
#pragma unroll
        for (int j = 0; j < 4; j++) bf[j] = *(const bf16x8*)&Bs[wn + j * 16 + lm][q * 8];
#pragma unroll
        for (int i = 0; i < 2; i++)
#pragma unroll
            for (int j = 0; j < 4; j++)
                acc[i][j] = __builtin_amdgcn_mfma_f32_16x16x32_bf16(af[i], bf[j], acc[i][j], 0, 0, 0);
    }
    // C store (bf16)
#pragma unroll
    for (int i = 0; i < 2; i++) {
        int row = rowBase + wm + i * 16 + q * 4;
#pragma unroll
        for (int j = 0; j < 4; j++) {
            int col = colBase + wn + j * 16 + lm;
#pragma unroll
            for (int r = 0; r < 4; r++)
                Cb[(row + r) * 512 + col] = f2bf(acc[i][j][r]);
        }
    }
    // node-att epilogue: head dot for this block's 64 rows
    float sa[4], da[4];
#pragma unroll
    for (int j = 0; j < 4; j++) {
        int col = colBase + wn + j * 16 + lm;
        sa[j] = atts[col]; da[j] = attd[col];
    }
#pragma unroll
    for (int i = 0; i < 2; i++) {
#pragma unroll
        for (int r = 0; r < 4; r++) {
            float ps = 0.f, pd = 0.f;
#pragma unroll
            for (int j = 0; j < 4; j++) {
                float c = acc[i][j][r];
                ps += c * sa[j]; pd += c * da[j];
            }
#pragma unroll
            for (int o = 1; o < 16; o <<= 1) { ps += __shfl_xor(ps, o); pd += __shfl_xor(pd, o); }
            if (lm == 0) {
                int row = wm + i * 16 + q * 4 + r;
                s_ps[w & 1][row] = ps; s_pd[w & 1][row] = pd;
            }
        }
    }
    __syncthreads();
    if (t < 64) {
        as_[(rowBase + t) * 4 + head] = s_ps[0][t] + s_ps[1][t];
    } else if (t < 128) {
        int row = t - 64;
        ad_[(rowBase + row) * 4 + head] = s_pd[0][row] + s_pd[1][row];
    }
}

// ---------------- kernel 5: FC MFMA + inline BN2+relu + mask + adj --------
__global__ __launch_bounds__(256) void k_fc_bn(const ushort* __restrict__ e2b,
        const float* __restrict__ stats, const float* __restrict__ g,
        const float* __restrict__ bb, const ushort* __restrict__ WfcT,
        const float* __restrict__ bfc, const int* __restrict__ mask,
        const float* __restrict__ adj, float* __restrict__ out) {
    __shared__ float s_scale[512], s_shift[512];
    __shared__ f32x4 s_acc[3][64][3];   // [wave-1][lane][jt]
    int t = threadIdx.x;
    int w = t >> 6, lane = t & 63;
    const float invn = 1.0f / (float)NN;
#pragma unroll
    for (int j = t; j < 512; j += 256) {
        float mu = stats[j] * invn;
        float var = stats[NF + j] * invn - mu * mu;
        float sc = rsqrtf(var + 1e-5f) * g[j];
        s_scale[j] = sc;
        s_shift[j] = bb[j] - mu * sc;
    }
    __syncthreads();
    int r0 = blockIdx.x * 16;
    int lm = lane & 15, q = lane >> 4;
    f32x4 acc[3] = {};
#pragma unroll
    for (int kk = 0; kk < 4; kk++) {
        int k0 = w * 128 + kk * 32;
        int jb = k0 + q * 8;
        uint4 a8 = *(const uint4*)&e2b[(r0 + lm) * 512 + jb];
        float av[8];
        av[0] = bflo(a8.x); av[1] = bfhi(a8.x); av[2] = bflo(a8.y); av[3] = bfhi(a8.y);
        av[4] = bflo(a8.z); av[5] = bfhi(a8.z); av[6] = bflo(a8.w); av[7] = bfhi(a8.w);
        ushort pa[8];
#pragma unroll
        for (int c = 0; c < 8; c++)
            pa[c] = f2bf(fmaxf(av[c] * s_scale[jb + c] + s_shift[jb + c], 0.f));
        bf16x8 af = *(const bf16x8*)pa;
#pragma unroll
        for (int jt = 0; jt < 3; jt++) {
            bf16x8 bf = *(const bf16x8*)&WfcT[(jt * 16 + lm) * 512 + k0 + q * 8];
            acc[jt] = __builtin_amdgcn_mfma_f32_16x16x32_bf16(af, bf, acc[jt], 0, 0, 0);
        }
    }
    if (w > 0) {
#pragma unroll
        for (int jt = 0; jt < 3; jt++) s_acc[w - 1][lane][jt] = acc[jt];
    }
    __syncthreads();
    if (w == 0) {
#pragma unroll
        for (int jt = 0; jt < 3; jt++) {
            acc[jt] += s_acc[0][lane][jt] + s_acc[1][lane][jt] + s_acc[2][lane][jt];
            int col = jt * 16 + lm;
            if (col < OUTE) {
#pragma unroll
                for (int r = 0; r < 4; r++) {
                    int n = r0 + q * 4 + r;
                    float v = acc[jt][r] + bfc[col];
                    v = mask[n] ? v : 0.f;
                    out[n * OUTE + col] = v + adj[n * OUTE + col];
                }
            }
        }
    }
}

// ---------------- host side ----------------------------------------------
extern "C" void kernel_launch(void* const* d_in, const int* in_sizes, int n_in,
                              void* d_out, int out_size, void* d_ws, size_t ws_size,
                              hipStream_t stream) {
    const float* x       = (const float*)d_in[0];
    const int*   ei      = (const int*)d_in[1];
    const float* pos     = (const float*)d_in[2];
    const int*   mask    = (const int*)d_in[3];
    const float* adj     = (const float*)d_in[4];
    const float* W1      = (const float*)d_in[5];
    const float* atts1   = (const float*)d_in[6];
    const float* attd1   = (const float*)d_in[7];
    const float* We1     = (const float*)d_in[8];
    const float* atte1   = (const float*)d_in[9];
    const float* bias1   = (const float*)d_in[10];
    const float* g1      = (const float*)d_in[11];
    const float* be1     = (const float*)d_in[12];
    const float* W2      = (const float*)d_in[13];
    const float* atts2   = (const float*)d_in[14];
    const float* attd2   = (const float*)d_in[15];
    const float* We2     = (const float*)d_in[16];
    const float* atte2   = (const float*)d_in[17];
    const float* bias2   = (const float*)d_in[18];
    const float* g2      = (const float*)d_in[19];
    const float* be2     = (const float*)d_in[20];
    const float* Wfc     = (const float*)d_in[21];
    const float* bfc     = (const float*)d_in[22];
    float* out = (float*)d_out;

    // workspace layout (float-element offsets; 16B-aligned blocks)
    char* ws = (char*)d_ws;
    int*    deg     = (int*)(ws);                       // 2560
    int*    ovf_cnt = (int*)(ws + 2560 * 4);            // 1 (pad 16)
    float*  stats   = (float*)(ws + 5120 * 4);          // 2048 (L1:1024, L2:1024)
    // ---- zero region = first 7168 elements ----
    float*  dote    = (float*)(ws + 7168 * 4);          // 8 (pad 16)
    int2*   csrp    = (int2*)(ws + 7184 * 4);           // 2560*256 int2
    int4*   ovf     = (int4*)(ws + 1317904 * 4);        // 163840 int4
    float*  as_     = (float*)(ws + 1973264 * 4);       // 10240
    float*  ad_     = (float*)(ws + 1983504 * 4);       // 10240
    ushort* t1b     = (ushort*)(ws + 1993744 * 4);      // 1310720 bf16
    ushort* hb      = (ushort*)(ws + 2649104 * 4);      // 1310720 bf16
    ushort* W2T     = (ushort*)(ws + 3304464 * 4);      // 262144 bf16
    ushort* WfcT    = (ushort*)(ws + 3435536 * 4);      // 24576 bf16

    hipMemsetAsync(d_ws, 0, 7168 * 4, stream);

    // CSR fill (single-pass) + weight prep + GEMM1+att (4 nodes/block)
    k_csr_gemm1<<<802 + NN / 4, 256, 0, stream>>>(ei, pos, deg, csrp, ovf_cnt, ovf,
                                                  We1, atte1, We2, atte2, dote,
                                                  Wfc, WfcT, W2, W2T,
                                                  x, W1, atts1, attd1, hb, as_, ad_);

    // ---- layer 1 ----
    k_edge_agg<<<NN / 2, 128, 0, stream>>>(deg, csrp, ovf_cnt, ovf, as_, ad_,
                                           dote, hb, bias1, t1b);
    k_bnstats<<<NN / 16, 256, 0, stream>>>(t1b, stats);

    // ---- layer 2 (BN1 inline in GEMM2 A-staging; node-att in epilogue) ----
    k_gemm2_bn_att<<<dim3(4, NN / 64), 256, 0, stream>>>(t1b, stats, g1, be1, W2T,
                                                         atts2, attd2, hb, as_, ad_);
    k_edge_agg<<<NN / 2, 128, 0, stream>>>(deg, csrp, ovf_cnt, ovf, as_, ad_,
                                           dote + 4, hb, bias2, t1b);
    k_bnstats<<<NN / 16, 256, 0, stream>>>(t1b, stats + 1024);

    // ---- head (BN2 inline in FC A-fragment load) ----
    k_fc_bn<<<NN / 16, 256, 0, stream>>>(t1b, stats + 1024, g2, be2, WfcT, bfc, mask, adj, out);
}